// Round 8
// baseline (327.771 us; speedup 1.0000x reference)
//
#include <hip/hip_runtime.h>

typedef __bf16 bf16;
typedef __bf16 bf16x8 __attribute__((ext_vector_type(8)));
typedef float f32x4 __attribute__((ext_vector_type(4)));

#define M_TOT 4096
#define D_IN  784
#define HALF  392
#define MID   1000
#define K0PAD 448   // 392 -> mult of 64
#define NPAD  1024  // 1000 padded

// ---------- fused prep: pack x-even -> A0 (bf16), transpose all weights, ldj ----------
__global__ void prep_k(const float* __restrict__ x, const float* __restrict__ ldj,
                       const float* __restrict__ W_in, const float* __restrict__ W_hid,
                       const float* __restrict__ W_out,
                       bf16* __restrict__ A0, bf16* __restrict__ WT0,
                       bf16* __restrict__ WTh, bf16* __restrict__ WT5,
                       float* __restrict__ y) {
  int b = blockIdx.x;
  int tid = threadIdx.x;
  if (b == 0 && tid == 0) y[(size_t)M_TOT * D_IN] = ldj[0];

  if (b < 8192) {  // pack
    int m = b >> 1;
    int k = (b & 1) * 256 + tid;
    if (k < K0PAD)
      A0[(size_t)m * K0PAD + k] = (k < HALF) ? (bf16)x[(size_t)m * D_IN + 2 * k] : (bf16)0.f;
    return;
  }
  int t = b - 8192;
  const float* W; bf16* WT; int K, N, Kpad, tn, tk;
  if (t < 448) {                 // W_in: (392 x 1000) -> (1024 x 448)
    W = W_in; WT = WT0; K = HALF; N = MID; Kpad = K0PAD;
    tn = t & 31; tk = t >> 5;
  } else if (t < 448 + 4096) {   // W_hid[i]: (1000 x 1000) -> (1024 x 1024)
    int u = t - 448; int i = u >> 10; u &= 1023;
    W = W_hid + (size_t)i * MID * MID; WT = WTh + (size_t)i * NPAD * NPAD;
    K = MID; N = MID; Kpad = NPAD;
    tn = u & 31; tk = u >> 5;
  } else {                       // W_out: (1000 x 392) -> (512 x 1024)
    int u = t - 4544;
    W = W_out; WT = WT5; K = MID; N = HALF; Kpad = NPAD;
    tn = u & 15; tk = u >> 4;
  }
  __shared__ float tb[32][33];
  int n0 = tn * 32, k0 = tk * 32;
  int tx = tid & 31, ty = tid >> 5;
#pragma unroll
  for (int r = 0; r < 4; ++r) {
    int k = k0 + ty + 8 * r, n = n0 + tx;
    tb[ty + 8 * r][tx] = (k < K && n < N) ? W[(size_t)k * N + n] : 0.f;
  }
  __syncthreads();
#pragma unroll
  for (int r = 0; r < 4; ++r) {
    int n = n0 + ty + 8 * r, k = k0 + tx;
    WT[(size_t)n * Kpad + k] = (bf16)tb[tx][ty + 8 * r];
  }
}

// ---------- register-direct GEMM: NO LDS, NO barriers ----------
// BM=64 x BN tile, 4 waves (wave tile 32 x BN/2). Both operands row-major,
// K-contiguous; MFMA frags load straight from global with dwordx4 + immediate
// offsets (lane groups {m,m+16,m+32,m+48} form fully-used 64B lines; L1 serves
// the wave-pair duplication). The K-loop is pure buffer_load <-> MFMA with
// compiler-scheduled vmcnt(N) -- no __syncthreads, no vmcnt(0) drains.
// Grid dim3(64, 8): bm = blockIdx.x, bn = blockIdx.y -> XCD = bm % 8.
// EPI=0: C = relu(A@BT^T + bias) bf16, stride NPAD.
// EPI=1: y pairs: y[m][2n]=x[m][2n]; y[m][2n+1]=x[m][2n+1]+acc+bias[n]  (n<HALF)
template <int BN, int EPI, int K>
__global__ __launch_bounds__(256, 2)
void gemm_k(const bf16* __restrict__ A, const bf16* __restrict__ BT,
            const float* __restrict__ bias, int bias_n,
            bf16* __restrict__ C,
            const float* __restrict__ x, float* __restrict__ y) {
  constexpr int MT = 2, NT = BN / 32;   // wave tile 32 x (BN/2)
  constexpr int KT = K / 64;
  const int tid = threadIdx.x, wave = tid >> 6, lane = tid & 63;
  const int bm = blockIdx.x, bn = blockIdx.y;
  const int mlane = lane & 15, quad = lane >> 4;
  const int wm = (wave & 1) * 32, wn = (wave >> 1) * (BN / 2);
  const int kq = quad * 8;

  // per-lane base pointers; all K-loop offsets are compile-time immediates
  const bf16* pa[MT];
  const bf16* pb[NT];
#pragma unroll
  for (int mt = 0; mt < MT; ++mt)
    pa[mt] = A + (size_t)(bm * 64 + wm + mt * 16 + mlane) * K + kq;
#pragma unroll
  for (int nt = 0; nt < NT; ++nt)
    pb[nt] = BT + (size_t)(bn * BN + wn + nt * 16 + mlane) * K + kq;

  f32x4 acc[MT][NT] = {};

#pragma unroll
  for (int kt = 0; kt < KT; ++kt) {
    bf16x8 af[2][MT], bfr[2][NT];
#pragma unroll
    for (int s = 0; s < 2; ++s) {
#pragma unroll
      for (int mt = 0; mt < MT; ++mt)
        af[s][mt] = *(const bf16x8*)(pa[mt] + kt * 64 + s * 32);
#pragma unroll
      for (int nt = 0; nt < NT; ++nt)
        bfr[s][nt] = *(const bf16x8*)(pb[nt] + kt * 64 + s * 32);
    }
#pragma unroll
    for (int s = 0; s < 2; ++s)
#pragma unroll
      for (int mt = 0; mt < MT; ++mt)
#pragma unroll
        for (int nt = 0; nt < NT; ++nt)
          acc[mt][nt] = __builtin_amdgcn_mfma_f32_16x16x32_bf16(
              af[s][mt], bfr[s][nt], acc[mt][nt], 0, 0, 0);
  }

  const int ng0 = bn * BN + wn + mlane;
  const int mg0 = bm * 64 + wm + quad * 4;

  if (EPI == 0) {
    float bv[NT];
#pragma unroll
    for (int nt = 0; nt < NT; ++nt) {
      int n = ng0 + nt * 16;
      bv[nt] = (n < bias_n) ? bias[n] : 0.f;
    }
#pragma unroll
    for (int mt = 0; mt < MT; ++mt)
#pragma unroll
      for (int nt = 0; nt < NT; ++nt)
#pragma unroll
        for (int r = 0; r < 4; ++r) {
          int m = mg0 + mt * 16 + r;
          int n = ng0 + nt * 16;
          float v = fmaxf(acc[mt][nt][r] + bv[nt], 0.f);
          C[(size_t)m * NPAD + n] = (bf16)v;
        }
  } else {
    const float2* x2 = (const float2*)x;
    float2* y2 = (float2*)y;
#pragma unroll
    for (int nt = 0; nt < NT; ++nt) {
      int n = ng0 + nt * 16;
      if (n < HALF) {
        float bb = bias[n];
#pragma unroll
        for (int mt = 0; mt < MT; ++mt)
#pragma unroll
          for (int r = 0; r < 4; ++r) {
            int m = mg0 + mt * 16 + r;
            size_t off = (size_t)m * (D_IN / 2) + n;
            float2 v = x2[off];
            v.y += acc[mt][nt][r] + bb;
            y2[off] = v;
          }
      }
    }
  }
}

extern "C" void kernel_launch(void* const* d_in, const int* in_sizes, int n_in,
                              void* d_out, int out_size, void* d_ws, size_t ws_size,
                              hipStream_t stream) {
  const float* x     = (const float*)d_in[0];
  const float* ldj   = (const float*)d_in[1];
  const float* W_in  = (const float*)d_in[2];
  const float* b_in  = (const float*)d_in[3];
  const float* W_hid = (const float*)d_in[4];
  const float* b_hid = (const float*)d_in[5];
  const float* W_out = (const float*)d_in[6];
  const float* b_out = (const float*)d_in[7];
  float* y = (float*)d_out;

  // workspace layout (bytes, 256-aligned)
  char* p = (char*)d_ws;
  bf16* A0  = (bf16*)(p + 0);           // 4096 x 448   (3,670,016 B)
  bf16* H0  = (bf16*)(p + 3670016);     // 4096 x 1024  (8,388,608 B)
  bf16* H1  = (bf16*)(p + 12058624);    // 4096 x 1024
  bf16* WT0 = (bf16*)(p + 20447232);    // 1024 x 448   (917,504 B)
  bf16* WTh = (bf16*)(p + 21364736);    // 4 x 1024 x 1024 (8,388,608 B)
  bf16* WT5 = (bf16*)(p + 29753344);    // 512 x 1024   (1,048,576 B)

  // --- prep: 1 launch (pack + all transposes + ldj) ---
  prep_k<<<dim3(8192 + 5056), 256, 0, stream>>>(x, ldj, W_in, W_hid, W_out,
                                                A0, WT0, WTh, WT5, y);

  // --- MLP: 6 GEMMs, 512 blocks each (2 blocks/CU), bm-major grid for XCD locality ---
  gemm_k<128, 0, K0PAD><<<dim3(64, 8), 256, 0, stream>>>(A0, WT0, b_in, MID, H0, nullptr, nullptr);
  gemm_k<128, 0, NPAD><<<dim3(64, 8), 256, 0, stream>>>(H0, WTh + 0 * (size_t)NPAD * NPAD, b_hid + 0 * MID, MID, H1, nullptr, nullptr);
  gemm_k<128, 0, NPAD><<<dim3(64, 8), 256, 0, stream>>>(H1, WTh + 1 * (size_t)NPAD * NPAD, b_hid + 1 * MID, MID, H0, nullptr, nullptr);
  gemm_k<128, 0, NPAD><<<dim3(64, 8), 256, 0, stream>>>(H0, WTh + 2 * (size_t)NPAD * NPAD, b_hid + 2 * MID, MID, H1, nullptr, nullptr);
  gemm_k<128, 0, NPAD><<<dim3(64, 8), 256, 0, stream>>>(H1, WTh + 3 * (size_t)NPAD * NPAD, b_hid + 3 * MID, MID, H0, nullptr, nullptr);
  // final: writes BOTH interleaved columns (even = copy of x, odd = second + shift)
  gemm_k<64, 1, NPAD><<<dim3(64, 8), 256, 0, stream>>>(H0, WT5, b_out, HALF, nullptr, x, y);
}

// Round 9
// 193.402 us; speedup vs baseline: 1.6948x; 1.6948x over previous
//
#include <hip/hip_runtime.h>

typedef __bf16 bf16;
typedef __bf16 bf16x8 __attribute__((ext_vector_type(8)));
typedef float f32x4 __attribute__((ext_vector_type(4)));

#define M_TOT 4096
#define D_IN  784
#define HALF  392
#define MID   1000
#define K0PAD 448   // 392 -> mult of 32 (14 k-chunks)
#define NPAD  1024  // 32 k-chunks

// ============ PACKED FRAGMENT LAYOUT ============
// Element (row r, k) of a K-contiguous operand lives at
//   ptr + (((r>>4)*KC + (k>>5))*64 + lane)*8 + (k&7),  lane = (r&15) | (((k>>3)&3)<<4)
// so one MFMA frag (16 rows x 32 k) = 64 lanes x 16B = ONE contiguous 1KB block.
// A frag load is a fully-coalesced global_load_dwordx4 (lane-linear).

// ---------- fused prep: pack x-even -> A0, all weights -> packed BT, ldj ----------
// blocks [0,256): A0 pack (one 16-row tile each)
// blocks [256, 256+5056): weight transpose+pack via 32x32 LDS tiles
__global__ void prep_k(const float* __restrict__ x, const float* __restrict__ ldj,
                       const float* __restrict__ W_in, const float* __restrict__ W_hid,
                       const float* __restrict__ W_out,
                       bf16* __restrict__ A0, bf16* __restrict__ WT0,
                       bf16* __restrict__ WTh, bf16* __restrict__ WT5,
                       float* __restrict__ y) {
  int b = blockIdx.x, tid = threadIdx.x;
  if (b == 0 && tid == 0) y[(size_t)M_TOT * D_IN] = ldj[0];

  if (b < 256) {  // pack x[:,0::2] rows [16b,16b+16) -> A0 packed, KC=14
    int t16 = b;
    int lane = tid & 63, kc0 = tid >> 6;
    int m = t16 * 16 + (lane & 15);
    int kbase = ((lane >> 4) & 3) * 8;
    const float* xr = x + (size_t)m * D_IN;
    for (int kc = kc0; kc < 14; kc += 4) {
      bf16* dst = A0 + ((size_t)(t16 * 14 + kc) * 64 + lane) * 8;
#pragma unroll
      for (int j = 0; j < 8; ++j) {
        int k = kc * 32 + kbase + j;
        dst[j] = (k < HALF) ? (bf16)xr[2 * k] : (bf16)0.f;
      }
    }
    return;
  }
  int t = b - 256;
  const float* W; bf16* WT; int K, N, KC, tn, tk;
  if (t < 448) {                 // W_in (392x1000) -> packed BT, 64 t16 x 14 kc
    W = W_in; WT = WT0; K = HALF; N = MID; KC = 14; tn = t & 31; tk = t >> 5;
  } else if (t < 4544) {         // W_hid[i] (1000x1000) -> packed, 64 t16 x 32 kc
    int u = t - 448, i = u >> 10; u &= 1023;
    W = W_hid + (size_t)i * MID * MID; WT = WTh + (size_t)i * (64 * 32 * 512);
    K = MID; N = MID; KC = 32; tn = u & 31; tk = u >> 5;
  } else {                       // W_out (1000x392) -> packed, 32 t16 x 32 kc
    int u = t - 4544;
    W = W_out; WT = WT5; K = MID; N = HALF; KC = 32; tn = u & 15; tk = u >> 4;
  }
  __shared__ float tb[32][33];
  int n0 = tn * 32, k0 = tk * 32;
  int tx = tid & 31, ty = tid >> 5;
#pragma unroll
  for (int r = 0; r < 4; ++r) {
    int k = k0 + ty + 8 * r, n = n0 + tx;
    tb[ty + 8 * r][tx] = (k < K && n < N) ? W[(size_t)k * N + n] : 0.f;
  }
  __syncthreads();
  // packed write: this 32x32 (k x n) tile = 2 t16-tiles x 1 kchunk
  int lane = tid >> 1;            // 0..127? no: tid<256 -> tid>>1 in 0..127 — mask:
  lane &= 63;                     // element group e=4*tid: lane=(e>>3)&63 = (tid>>1)&63
  int t16h = tid >> 7;            // e>>9 = tid>>7 (0 or 1)
  int jb = (tid & 1) * 4;
  int nl = lane & 15, klo = ((lane >> 4) & 3) * 8;
  int t16g = tn * 2 + t16h;
  bf16* dst = WT + ((size_t)(t16g * KC + tk) * 64 + lane) * 8 + jb;
#pragma unroll
  for (int i = 0; i < 4; ++i) dst[i] = (bf16)tb[klo + jb + i][t16h * 16 + nl];
}

// ---------- register-direct GEMM on PACKED operands: no LDS, no barriers ----------
// BM=64 x BN, 4 waves, wave tile 32 x BN/2 (MT=2, NT=BN/32).
// K-loop: distance-2 register prefetch (3 frag buffer sets, ~12 loads in flight),
// every load a fully-coalesced contiguous-1KB dwordx4. Compiler-scheduled vmcnt.
// Grid dim3(64, 8): bm-major -> XCD = bm % 8 (locality heuristic only).
// EPI=0: C = relu(A@BT^T + bias) written in PACKED layout (next K = NPAD, KC=32).
// EPI=1: y pairs: y[m][2n]=x[m][2n]; y[m][2n+1]=x[m][2n+1]+acc+bias[n] (n<HALF)
template <int BN, int EPI, int K>
__global__ __launch_bounds__(256, 2)
void gemm_k(const bf16* __restrict__ A, const bf16* __restrict__ BT,
            const float* __restrict__ bias, int bias_n,
            bf16* __restrict__ C,
            const float* __restrict__ x, float* __restrict__ y) {
  constexpr int MT = 2, NT = BN / 32;
  constexpr int KC = K / 32;
  const int tid = threadIdx.x, wave = tid >> 6, lane = tid & 63;
  const int bm = blockIdx.x, bn = blockIdx.y;
  const int mlane = lane & 15, quad = lane >> 4;
  const int wn = (wave >> 1) * (BN / 2);
  const int t16a = bm * 4 + (wave & 1) * 2;
  const int t16b = bn * (BN / 16) + (wave >> 1) * NT;

  const bf16* pa = A + (size_t)lane * 8;
  const bf16* pb = BT + (size_t)lane * 8;

  f32x4 acc[MT][NT] = {};
  bf16x8 a0[MT], b0[NT], a1[MT], b1[NT], a2[MT], b2[NT];

#define LDF(aa, bb, c) do { \
    _Pragma("unroll") for (int mt = 0; mt < MT; ++mt) \
      aa[mt] = *(const bf16x8*)(pa + ((size_t)((t16a + mt) * KC + (c)) << 9)); \
    _Pragma("unroll") for (int nt = 0; nt < NT; ++nt) \
      bb[nt] = *(const bf16x8*)(pb + ((size_t)((t16b + nt) * KC + (c)) << 9)); \
  } while (0)

  LDF(a0, b0, 0);
  if (KC > 1) LDF(a1, b1, 1);
#pragma unroll
  for (int c = 0; c < KC; ++c) {
    if (c + 2 < KC) LDF(a2, b2, c + 2);
#pragma unroll
    for (int mt = 0; mt < MT; ++mt)
#pragma unroll
      for (int nt = 0; nt < NT; ++nt)
        acc[mt][nt] = __builtin_amdgcn_mfma_f32_16x16x32_bf16(
            a0[mt], b0[nt], acc[mt][nt], 0, 0, 0);
#pragma unroll
    for (int mt = 0; mt < MT; ++mt) { a0[mt] = a1[mt]; a1[mt] = a2[mt]; }
#pragma unroll
    for (int nt = 0; nt < NT; ++nt) { b0[nt] = b1[nt]; b1[nt] = b2[nt]; }
  }
#undef LDF

  if (EPI == 0) {
    // write relu(acc+bias) in packed layout; next layer K = NPAD -> KC = 32
    const int mrow = quad * 4;
#pragma unroll
    for (int nt = 0; nt < NT; ++nt) {
      const int nbase = bn * BN + wn + nt * 16;
      const int n = nbase + mlane;
      const float bv = (n < bias_n) ? bias[n] : 0.f;
      const int kc = nbase >> 5;
      const int lane2hi = ((nbase & 16) + mlane) >> 3;  // 0..3
      const int j = mlane & 7;
#pragma unroll
      for (int mt = 0; mt < MT; ++mt) {
        bf16* dst = C + ((size_t)((t16a + mt) * 32 + kc) << 9) + j;
#pragma unroll
        for (int r = 0; r < 4; ++r) {
          float v = fmaxf(acc[mt][nt][r] + bv, 0.f);
          const int lane2 = (mrow + r) | (lane2hi << 4);
          dst[lane2 * 8] = (bf16)v;
        }
      }
    }
  } else {
    const float2* x2 = (const float2*)x;
    float2* y2 = (float2*)y;
#pragma unroll
    for (int nt = 0; nt < NT; ++nt) {
      int n = bn * BN + wn + nt * 16 + mlane;
      if (n < HALF) {
        float bb = bias[n];
#pragma unroll
        for (int mt = 0; mt < MT; ++mt)
#pragma unroll
          for (int r = 0; r < 4; ++r) {
            int m = bm * 64 + (wave & 1) * 32 + mt * 16 + quad * 4 + r;
            size_t off = (size_t)m * (D_IN / 2) + n;
            float2 v = x2[off];
            v.y += acc[mt][nt][r] + bb;
            y2[off] = v;
          }
      }
    }
  }
}

extern "C" void kernel_launch(void* const* d_in, const int* in_sizes, int n_in,
                              void* d_out, int out_size, void* d_ws, size_t ws_size,
                              hipStream_t stream) {
  const float* x     = (const float*)d_in[0];
  const float* ldj   = (const float*)d_in[1];
  const float* W_in  = (const float*)d_in[2];
  const float* b_in  = (const float*)d_in[3];
  const float* W_hid = (const float*)d_in[4];
  const float* b_hid = (const float*)d_in[5];
  const float* W_out = (const float*)d_in[6];
  const float* b_out = (const float*)d_in[7];
  float* y = (float*)d_out;

  // workspace layout (bytes, 256-aligned) — all buffers in packed-frag layout
  char* p = (char*)d_ws;
  bf16* A0  = (bf16*)(p + 0);           // 256 t16 x 14 kc  (3,670,016 B)
  bf16* H0  = (bf16*)(p + 3670016);     // 256 t16 x 32 kc  (8,388,608 B)
  bf16* H1  = (bf16*)(p + 12058624);    // 256 t16 x 32 kc
  bf16* WT0 = (bf16*)(p + 20447232);    // 64 t16 x 14 kc   (917,504 B)
  bf16* WTh = (bf16*)(p + 21364736);    // 4 x (64 t16 x 32 kc) (8,388,608 B)
  bf16* WT5 = (bf16*)(p + 29753344);    // 32 t16 x 32 kc   (1,048,576 B)

  // --- prep: 1 launch (pack + all transposes + ldj) ---
  prep_k<<<dim3(256 + 5056), 256, 0, stream>>>(x, ldj, W_in, W_hid, W_out,
                                               A0, WT0, WTh, WT5, y);

  // --- MLP: 6 GEMMs, 512 blocks each (2 blocks/CU), bm-major grid ---
  gemm_k<128, 0, K0PAD><<<dim3(64, 8), 256, 0, stream>>>(A0, WT0, b_in, MID, H0, nullptr, nullptr);
  gemm_k<128, 0, NPAD><<<dim3(64, 8), 256, 0, stream>>>(H0, WTh + 0 * (size_t)(64 * 32 * 512), b_hid + 0 * MID, MID, H1, nullptr, nullptr);
  gemm_k<128, 0, NPAD><<<dim3(64, 8), 256, 0, stream>>>(H1, WTh + 1 * (size_t)(64 * 32 * 512), b_hid + 1 * MID, MID, H0, nullptr, nullptr);
  gemm_k<128, 0, NPAD><<<dim3(64, 8), 256, 0, stream>>>(H0, WTh + 2 * (size_t)(64 * 32 * 512), b_hid + 2 * MID, MID, H1, nullptr, nullptr);
  gemm_k<128, 0, NPAD><<<dim3(64, 8), 256, 0, stream>>>(H1, WTh + 3 * (size_t)(64 * 32 * 512), b_hid + 3 * MID, MID, H0, nullptr, nullptr);
  // final: writes BOTH interleaved columns (even = copy of x, odd = second + shift)
  gemm_k<64, 1, NPAD><<<dim3(64, 8), 256, 0, stream>>>(H0, WT5, b_out, HALF, nullptr, x, y);
}

// Round 10
// 169.399 us; speedup vs baseline: 1.9349x; 1.1417x over previous
//
#include <hip/hip_runtime.h>

typedef __bf16 bf16;
typedef __bf16 bf16x8 __attribute__((ext_vector_type(8)));
typedef float f32x4 __attribute__((ext_vector_type(4)));

#define M_TOT 4096
#define D_IN  784
#define HALF  392
#define MID   1000
#define K0PAD 448   // 392 -> mult of 64
#define NPAD  1024  // 1000 padded

// ---------- async global->LDS 16B ----------
__device__ __forceinline__ void g2l16(const bf16* g, bf16* l) {
  __builtin_amdgcn_global_load_lds(
      (__attribute__((address_space(1))) void*)(g),
      (__attribute__((address_space(3))) void*)(l),
      16, 0, 0);
}

// ---------- fused prep: pack x-even -> A0 (bf16), transpose all weights, ldj ----------
__global__ void prep_k(const float* __restrict__ x, const float* __restrict__ ldj,
                       const float* __restrict__ W_in, const float* __restrict__ W_hid,
                       const float* __restrict__ W_out,
                       bf16* __restrict__ A0, bf16* __restrict__ WT0,
                       bf16* __restrict__ WTh, bf16* __restrict__ WT5,
                       float* __restrict__ y) {
  int b = blockIdx.x;
  int tid = threadIdx.x;
  if (b == 0 && tid == 0) y[(size_t)M_TOT * D_IN] = ldj[0];

  if (b < 8192) {  // pack
    int m = b >> 1;
    int k = (b & 1) * 256 + tid;
    if (k < K0PAD)
      A0[(size_t)m * K0PAD + k] = (k < HALF) ? (bf16)x[(size_t)m * D_IN + 2 * k] : (bf16)0.f;
    return;
  }
  int t = b - 8192;
  const float* W; bf16* WT; int K, N, Kpad, tn, tk;
  if (t < 448) {                 // W_in: (392 x 1000) -> (1024 x 448)
    W = W_in; WT = WT0; K = HALF; N = MID; Kpad = K0PAD;
    tn = t & 31; tk = t >> 5;
  } else if (t < 448 + 4096) {   // W_hid[i]: (1000 x 1000) -> (1024 x 1024)
    int u = t - 448; int i = u >> 10; u &= 1023;
    W = W_hid + (size_t)i * MID * MID; WT = WTh + (size_t)i * NPAD * NPAD;
    K = MID; N = MID; Kpad = NPAD;
    tn = u & 31; tk = u >> 5;
  } else {                       // W_out: (1000 x 392) -> (512 x 1024)
    int u = t - 4544;
    W = W_out; WT = WT5; K = MID; N = HALF; Kpad = NPAD;
    tn = u & 15; tk = u >> 4;
  }
  __shared__ float tb[32][33];
  int n0 = tn * 32, k0 = tk * 32;
  int tx = tid & 31, ty = tid >> 5;
#pragma unroll
  for (int r = 0; r < 4; ++r) {
    int k = k0 + ty + 8 * r, n = n0 + tx;
    tb[ty + 8 * r][tx] = (k < K && n < N) ? W[(size_t)k * N + n] : 0.f;
  }
  __syncthreads();
#pragma unroll
  for (int r = 0; r < 4; ++r) {
    int n = n0 + ty + 8 * r, k = k0 + tx;
    WT[(size_t)n * Kpad + k] = (bf16)tb[tx][ty + 8 * r];
  }
}

// ---------- GEMM: BM=64 x BN=64 tile, BK=64, 4 waves, XOR-swizzled LDS ----------
// Grid dim3(64, NB): bm = blockIdx.x, bn = blockIdx.y. Linear id = bm + 64*bn
// -> XCD = bm % 8 (locality heuristic only; correctness mapping-independent).
// 1024 blocks for hidden layers -> 4 blocks/CU, 16 waves/CU: barrier drains of
// one block are hidden by MFMA of the other three (m114 co-scheduling).
// EPI=0: C = relu(A@BT^T + bias) bf16, stride NPAD.
// EPI=1: y pairs: y[m][2n]=x[m][2n]; y[m][2n+1]=x[m][2n+1]+acc+bias[n]  (n<HALF)
template <int BM, int BN, int EPI, int K>
__global__ __launch_bounds__(256, 4)
void gemm_k(const bf16* __restrict__ A, const bf16* __restrict__ BT,
            const float* __restrict__ bias, int bias_n,
            bf16* __restrict__ C,
            const float* __restrict__ x, float* __restrict__ y) {
  constexpr int BK = 64;
  constexpr int MT = BM / 32, NT = BN / 32;      // frags per wave (m, n)
  constexpr int KT = K / BK;
  __shared__ bf16 ldsA[BM * BK];
  __shared__ bf16 ldsB[BN * BK];
  const int tid = threadIdx.x, wave = tid >> 6, lane = tid & 63;
  const int bm = blockIdx.x, bn = blockIdx.y;

  // staging: 8 lanes/row (64 cols * 2B = 128B); global 16B-group XOR-swizzled by row.
  const int srow = lane >> 3;
  const int sq = (lane & 7) ^ srow;
  const bf16* gA = A + ((size_t)bm * BM + wave * (BM / 4) + srow) * K + sq * 8;
  const bf16* gB = BT + ((size_t)bn * BN + wave * (BN / 4) + srow) * K + sq * 8;
  bf16* lA = &ldsA[wave * (BM / 4) * BK];
  bf16* lB = &ldsB[wave * (BN / 4) * BK];

  const int mlane = lane & 15, quad = lane >> 4;
  const int wm = (wave & 1) * (BM / 2), wn = (wave >> 1) * (BN / 2);
  const int axor = mlane & 7;
  const bf16* raBase = &ldsA[(wm + mlane) * BK];
  const bf16* rbBase = &ldsB[(wn + mlane) * BK];

  f32x4 acc[MT][NT] = {};

  // stage tile 0
#pragma unroll
  for (int i = 0; i < BM / 32; ++i) g2l16(gA + (size_t)(8 * i) * K, lA + (8 * i) * BK);
#pragma unroll
  for (int i = 0; i < BN / 32; ++i) g2l16(gB + (size_t)(8 * i) * K, lB + (8 * i) * BK);

  for (int kt = 0; kt < KT; ++kt) {
    __syncthreads();  // staging of tile kt complete
    bf16x8 af[2][MT], bfr[2][NT];
#pragma unroll
    for (int s = 0; s < 2; ++s) {
      const int co = ((s * 4 + quad) ^ axor) * 8;
#pragma unroll
      for (int i = 0; i < MT; ++i) af[s][i] = *(const bf16x8*)(raBase + i * 16 * BK + co);
#pragma unroll
      for (int i = 0; i < NT; ++i) bfr[s][i] = *(const bf16x8*)(rbBase + i * 16 * BK + co);
    }
    __syncthreads();  // all waves done reading LDS
    if (kt + 1 < KT) {
      const size_t off = (size_t)(kt + 1) * BK;
#pragma unroll
      for (int i = 0; i < BM / 32; ++i) g2l16(gA + off + (size_t)(8 * i) * K, lA + (8 * i) * BK);
#pragma unroll
      for (int i = 0; i < BN / 32; ++i) g2l16(gB + off + (size_t)(8 * i) * K, lB + (8 * i) * BK);
    }
#pragma unroll
    for (int s = 0; s < 2; ++s)
#pragma unroll
      for (int mt = 0; mt < MT; ++mt)
#pragma unroll
        for (int nt = 0; nt < NT; ++nt)
          acc[mt][nt] = __builtin_amdgcn_mfma_f32_16x16x32_bf16(
              af[s][mt], bfr[s][nt], acc[mt][nt], 0, 0, 0);
  }

  const int ng0 = bn * BN + wn + mlane;
  const int mg0 = bm * BM + wm + quad * 4;

  if (EPI == 0) {
    float bv[NT];
#pragma unroll
    for (int nt = 0; nt < NT; ++nt) {
      int n = ng0 + nt * 16;
      bv[nt] = (n < bias_n) ? bias[n] : 0.f;
    }
#pragma unroll
    for (int mt = 0; mt < MT; ++mt)
#pragma unroll
      for (int nt = 0; nt < NT; ++nt)
#pragma unroll
        for (int r = 0; r < 4; ++r) {
          int m = mg0 + mt * 16 + r;
          int n = ng0 + nt * 16;
          float v = fmaxf(acc[mt][nt][r] + bv[nt], 0.f);
          C[(size_t)m * NPAD + n] = (bf16)v;
        }
  } else {
    const float2* x2 = (const float2*)x;
    float2* y2 = (float2*)y;
#pragma unroll
    for (int nt = 0; nt < NT; ++nt) {
      int n = ng0 + nt * 16;
      if (n < HALF) {
        float bb = bias[n];
#pragma unroll
        for (int mt = 0; mt < MT; ++mt)
#pragma unroll
          for (int r = 0; r < 4; ++r) {
            int m = mg0 + mt * 16 + r;
            size_t off = (size_t)m * (D_IN / 2) + n;
            float2 v = x2[off];
            v.y += acc[mt][nt][r] + bb;
            y2[off] = v;
          }
      }
    }
  }
}

extern "C" void kernel_launch(void* const* d_in, const int* in_sizes, int n_in,
                              void* d_out, int out_size, void* d_ws, size_t ws_size,
                              hipStream_t stream) {
  const float* x     = (const float*)d_in[0];
  const float* ldj   = (const float*)d_in[1];
  const float* W_in  = (const float*)d_in[2];
  const float* b_in  = (const float*)d_in[3];
  const float* W_hid = (const float*)d_in[4];
  const float* b_hid = (const float*)d_in[5];
  const float* W_out = (const float*)d_in[6];
  const float* b_out = (const float*)d_in[7];
  float* y = (float*)d_out;

  // workspace layout (bytes, 256-aligned)
  char* p = (char*)d_ws;
  bf16* A0  = (bf16*)(p + 0);           // 4096 x 448   (3,670,016 B)
  bf16* H0  = (bf16*)(p + 3670016);     // 4096 x 1024  (8,388,608 B)
  bf16* H1  = (bf16*)(p + 12058624);    // 4096 x 1024
  bf16* WT0 = (bf16*)(p + 20447232);    // 1024 x 448   (917,504 B)
  bf16* WTh = (bf16*)(p + 21364736);    // 4 x 1024 x 1024 (8,388,608 B)
  bf16* WT5 = (bf16*)(p + 29753344);    // 512 x 1024   (1,048,576 B)

  // --- prep: 1 launch (pack + all transposes + ldj) ---
  prep_k<<<dim3(8192 + 5056), 256, 0, stream>>>(x, ldj, W_in, W_hid, W_out,
                                                A0, WT0, WTh, WT5, y);

  // --- MLP: 6 GEMMs, 64x64 tiles, 1024 blocks (4 blocks/CU), bm-major grid ---
  gemm_k<64, 64, 0, K0PAD><<<dim3(64, 16), 256, 0, stream>>>(A0, WT0, b_in, MID, H0, nullptr, nullptr);
  gemm_k<64, 64, 0, NPAD><<<dim3(64, 16), 256, 0, stream>>>(H0, WTh + 0 * (size_t)NPAD * NPAD, b_hid + 0 * MID, MID, H1, nullptr, nullptr);
  gemm_k<64, 64, 0, NPAD><<<dim3(64, 16), 256, 0, stream>>>(H1, WTh + 1 * (size_t)NPAD * NPAD, b_hid + 1 * MID, MID, H0, nullptr, nullptr);
  gemm_k<64, 64, 0, NPAD><<<dim3(64, 16), 256, 0, stream>>>(H0, WTh + 2 * (size_t)NPAD * NPAD, b_hid + 2 * MID, MID, H1, nullptr, nullptr);
  gemm_k<64, 64, 0, NPAD><<<dim3(64, 16), 256, 0, stream>>>(H1, WTh + 3 * (size_t)NPAD * NPAD, b_hid + 3 * MID, MID, H0, nullptr, nullptr);
  // final: writes BOTH interleaved columns (even = copy of x, odd = second + shift)
  gemm_k<64, 64, 1, NPAD><<<dim3(64, 8), 256, 0, stream>>>(H0, WT5, b_out, HALF, nullptr, x, y);
}